// Round 1
// baseline (757.363 us; speedup 1.0000x reference)
//
#include <hip/hip_runtime.h>

// Squeeze-Excite: in [B=32, H=112, W=112, C=256] fp32
//   se = sigmoid(relu(mean_hw(in) @ w1 + b1) @ w2 + b2)
//   out = in * se[b, :]
// Memory-bound: 2 reads + 1 write of 411 MB => ~196 us floor @ 6.3 TB/s.

#define B_  32
#define HW_ 12544            // 112*112
#define C_  256
#define CR_ 16               // C / r
#define BLOCKS_PER_B 64
#define CHUNKS_PER_BLOCK 49  // HW_/4 rows-chunks / BLOCKS_PER_B = 12544/4/64

// ---------------------------------------------------------------------------
// Kernel 1: per-(b,c) spatial sum. Each block-iteration covers 4 spatial rows
// (1024 floats) as 256 float4 loads; thread t always owns channels
// (4t mod 256)..+3, so it accumulates in 4 registers across 49 iterations.
// Conflict-free LDS tree (4 groups x 64 float4), then 1 atomicAdd/thread.
// ---------------------------------------------------------------------------
__global__ __launch_bounds__(256) void se_reduce(const float* __restrict__ in,
                                                 float* __restrict__ sums) {
    const int b   = blockIdx.x >> 6;       // 64 blocks per batch
    const int blk = blockIdx.x & 63;
    const int t   = threadIdx.x;

    const float4* base = (const float4*)(in + (size_t)b * HW_ * C_);
    float4 acc = make_float4(0.f, 0.f, 0.f, 0.f);
    for (int i = 0; i < CHUNKS_PER_BLOCK; ++i) {
        const float4 v = base[(size_t)(blk + i * BLOCKS_PER_B) * 256 + t];
        acc.x += v.x; acc.y += v.y; acc.z += v.z; acc.w += v.w;
    }

    // group g = t>>6; within a group the 64 threads cover all 256 channels once
    __shared__ float4 s4[4][64];
    s4[t >> 6][t & 63] = acc;
    __syncthreads();

    const float* sf = (const float*)s4;    // sf[g*256 + c]
    const float v = sf[t] + sf[256 + t] + sf[512 + t] + sf[768 + t];
    atomicAdd(&sums[b * C_ + t], v);
}

// ---------------------------------------------------------------------------
// Kernel 2: tiny bottleneck MLP, one block of 256 threads.
//   mean[32][256] in LDS -> h[32][16] = relu(mean@w1+b1) -> se = sigmoid(h@w2+b2)
// ---------------------------------------------------------------------------
__global__ __launch_bounds__(256) void se_mlp(const float* __restrict__ sums,
                                              const float* __restrict__ w1,
                                              const float* __restrict__ b1,
                                              const float* __restrict__ w2,
                                              const float* __restrict__ b2,
                                              float* __restrict__ se) {
    __shared__ float mean[B_][C_];   // 32 KB
    __shared__ float h[B_][CR_];     // 2 KB
    const int t = threadIdx.x;
    const float inv = 1.0f / (float)HW_;

    for (int b = 0; b < B_; ++b)
        mean[b][t] = sums[b * C_ + t] * inv;
    __syncthreads();

    // stage 1: 512 outputs, 2 per thread, dot length 256
    int idx = t;
    for (int rep = 0; rep < 2; ++rep, idx += 256) {
        const int b = idx >> 4, j = idx & 15;
        float acc = b1[j];
        for (int k = 0; k < C_; ++k)
            acc = fmaf(mean[b][k], w1[k * CR_ + j], acc);
        h[b][j] = fmaxf(acc, 0.f);
    }
    __syncthreads();

    // stage 2: se[b][t] = sigmoid(b2[t] + sum_j h[b][j] * w2[j*256 + t])
    const float bias = b2[t];
    for (int b = 0; b < B_; ++b) {
        float acc = bias;
        #pragma unroll
        for (int j = 0; j < CR_; ++j)
            acc = fmaf(h[b][j], w2[j * C_ + t], acc);
        se[b * C_ + t] = 1.0f / (1.0f + __expf(-acc));
    }
}

// ---------------------------------------------------------------------------
// Kernel 3: out = in * se (broadcast over spatial). Same geometry as kernel 1;
// each thread loads its fixed 4-channel se float4 once, then streams.
// ---------------------------------------------------------------------------
__global__ __launch_bounds__(256) void se_scale(const float* __restrict__ in,
                                                const float* __restrict__ se,
                                                float* __restrict__ out) {
    const int b   = blockIdx.x >> 6;
    const int blk = blockIdx.x & 63;
    const int t   = threadIdx.x;

    const float4 s = ((const float4*)(se + b * C_))[t & 63];
    const float4* src = (const float4*)(in  + (size_t)b * HW_ * C_);
    float4*       dst = (float4*)      (out + (size_t)b * HW_ * C_);

    for (int i = 0; i < CHUNKS_PER_BLOCK; ++i) {
        const size_t idx = (size_t)(blk + i * BLOCKS_PER_B) * 256 + t;
        float4 v = src[idx];
        v.x *= s.x; v.y *= s.y; v.z *= s.z; v.w *= s.w;
        dst[idx] = v;
    }
}

extern "C" void kernel_launch(void* const* d_in, const int* in_sizes, int n_in,
                              void* d_out, int out_size, void* d_ws, size_t ws_size,
                              hipStream_t stream) {
    const float* in = (const float*)d_in[0];
    const float* w1 = (const float*)d_in[1];
    const float* b1 = (const float*)d_in[2];
    const float* w2 = (const float*)d_in[3];
    const float* b2 = (const float*)d_in[4];
    float* out  = (float*)d_out;
    float* sums = (float*)d_ws;          // [32*256] accumulators
    float* se   = sums + B_ * C_;        // [32*256] scale factors

    // ws is re-poisoned to 0xAA before every timed launch -> zero the accumulator
    hipMemsetAsync(sums, 0, B_ * C_ * sizeof(float), stream);

    se_reduce<<<B_ * BLOCKS_PER_B, 256, 0, stream>>>(in, sums);
    se_mlp<<<1, 256, 0, stream>>>(sums, w1, b1, w2, b2, se);
    se_scale<<<B_ * BLOCKS_PER_B, 256, 0, stream>>>(in, se, out);
}

// Round 2
// 713.175 us; speedup vs baseline: 1.0620x; 1.0620x over previous
//
#include <hip/hip_runtime.h>

// Squeeze-Excite: in [B=32, H=112, W=112, C=256] fp32
//   se = sigmoid(relu(mean_hw(in) @ w1 + b1) @ w2 + b2);  out = in * se[b,:]
//
// Strategy (round 2): batch-grouped L3 pipelining. Process 8 batches (103 MB)
// per group: reduce(g) streams input through L3, scale(g) re-reads it from L3
// (non-temporal stores keep the output stream from evicting it). Cuts the
// structural HBM traffic from 1.23 GB toward 822 MB (~131 us floor @ 6.3 TB/s).
// No atomics / no memset: blocks write private partial sums into ws.

#define B_  32
#define HW_ 12544            // 112*112
#define C_  256
#define CR_ 16               // C/r
#define BLOCKS_PER_B 64
#define CHUNKS 49            // HW_*C_/4 float4 per batch / 256 / BLOCKS_PER_B
#define GB 8                 // batches per group
#define GROUPS 4

typedef float f4 __attribute__((ext_vector_type(4)));

// ---------------------------------------------------------------------------
// Kernel 1: per-(b,blk) partial channel sums -> partials[(b*64+blk)*256 + c].
// Thread t owns channels 4*(t&63)..+3; LDS tree folds the 4 thread-groups.
// Normal (temporal) loads: we WANT these lines resident in L3 for se_scale.
// ---------------------------------------------------------------------------
__global__ __launch_bounds__(256) void se_reduce(const float* __restrict__ in,
                                                 float* __restrict__ partials,
                                                 int b0) {
    const int b   = b0 + (blockIdx.x >> 6);
    const int blk = blockIdx.x & 63;
    const int t   = threadIdx.x;

    const f4* base = (const f4*)(in + (size_t)b * HW_ * C_);
    f4 acc = (f4)0.0f;
    for (int i = 0; i < CHUNKS; ++i) {
        acc += base[(size_t)(blk + i * BLOCKS_PER_B) * 256 + t];
    }

    __shared__ f4 s4[4][64];
    s4[t >> 6][t & 63] = acc;
    __syncthreads();

    const float* sf = (const float*)s4;          // sf[g*256 + c]
    const float v = sf[t] + sf[256 + t] + sf[512 + t] + sf[768 + t];
    partials[((size_t)b * BLOCKS_PER_B + blk) * C_ + t] = v;
}

// ---------------------------------------------------------------------------
// Kernel 2: one block per batch. Fold 64 partials -> mean, bottleneck MLP,
// sigmoid -> se[b][c]. All operands tiny (L2/L3-resident).
// ---------------------------------------------------------------------------
__global__ __launch_bounds__(256) void se_mlp(const float* __restrict__ partials,
                                              const float* __restrict__ w1,
                                              const float* __restrict__ b1,
                                              const float* __restrict__ w2,
                                              const float* __restrict__ b2,
                                              float* __restrict__ se,
                                              int b0) {
    const int b = b0 + blockIdx.x;
    const int t = threadIdx.x;

    __shared__ float mean_s[C_];
    __shared__ float ph[CR_][17];                // +1 pad
    __shared__ float h_s[CR_];

    const float* base = partials + (size_t)b * BLOCKS_PER_B * C_;
    float s = 0.f;
    for (int blk = 0; blk < BLOCKS_PER_B; ++blk)
        s += base[blk * C_ + t];
    mean_s[t] = s * (1.0f / (float)HW_);
    __syncthreads();

    // stage 1: h[j] = relu(b1[j] + sum_k mean[k]*w1[k,j]); 16 j x 16 k-slices
    const int g = t >> 4, j = t & 15;
    float a = 0.f;
    #pragma unroll
    for (int kk = 0; kk < 16; ++kk) {
        const int k = g * 16 + kk;
        a = fmaf(mean_s[k], w1[k * CR_ + j], a);
    }
    ph[j][g] = a;
    __syncthreads();
    if (t < CR_) {
        float acc = b1[t];
        #pragma unroll
        for (int g2 = 0; g2 < 16; ++g2) acc += ph[t][g2];
        h_s[t] = fmaxf(acc, 0.f);
    }
    __syncthreads();

    // stage 2: se[b][t] = sigmoid(b2[t] + sum_j h[j]*w2[j,t])
    float acc = b2[t];
    #pragma unroll
    for (int j2 = 0; j2 < CR_; ++j2)
        acc = fmaf(h_s[j2], w2[j2 * C_ + t], acc);
    se[b * C_ + t] = 1.0f / (1.0f + __expf(-acc));
}

// ---------------------------------------------------------------------------
// Kernel 3: out = in * se. Non-temporal load (line dead after read) and
// non-temporal store (never re-read) to avoid evicting the group's input.
// ---------------------------------------------------------------------------
__global__ __launch_bounds__(256) void se_scale(const float* __restrict__ in,
                                                const float* __restrict__ se,
                                                float* __restrict__ out,
                                                int b0) {
    const int b   = b0 + (blockIdx.x >> 6);
    const int blk = blockIdx.x & 63;
    const int t   = threadIdx.x;

    const f4 s = ((const f4*)(se + b * C_))[t & 63];
    const f4* src = (const f4*)(in  + (size_t)b * HW_ * C_);
    f4*       dst = (f4*)      (out + (size_t)b * HW_ * C_);

    for (int i = 0; i < CHUNKS; ++i) {
        const size_t idx = (size_t)(blk + i * BLOCKS_PER_B) * 256 + t;
        f4 v = __builtin_nontemporal_load(src + idx);
        v = v * s;
        __builtin_nontemporal_store(v, dst + idx);
    }
}

extern "C" void kernel_launch(void* const* d_in, const int* in_sizes, int n_in,
                              void* d_out, int out_size, void* d_ws, size_t ws_size,
                              hipStream_t stream) {
    const float* in = (const float*)d_in[0];
    const float* w1 = (const float*)d_in[1];
    const float* b1 = (const float*)d_in[2];
    const float* w2 = (const float*)d_in[3];
    const float* b2 = (const float*)d_in[4];
    float* out      = (float*)d_out;
    float* partials = (float*)d_ws;                       // [32*64*256] = 2 MB
    float* se       = partials + B_ * BLOCKS_PER_B * C_;  // [32*256]

    for (int g = 0; g < GROUPS; ++g) {
        const int b0 = g * GB;
        se_reduce<<<GB * BLOCKS_PER_B, 256, 0, stream>>>(in, partials, b0);
        se_mlp<<<GB, 256, 0, stream>>>(partials, w1, b1, w2, b2, se, b0);
        se_scale<<<GB * BLOCKS_PER_B, 256, 0, stream>>>(in, se, out, b0);
    }
}